// Round 5
// baseline (204.172 us; speedup 1.0000x reference)
//
#include <hip/hip_runtime.h>

// Problem constants: N=8, H=512, W=512, K=1, NF=100000, D=8
#define NN 8
#define HH 512
#define WW 512
#define DD 8

constexpr int HW    = HH * WW;       // 262144 (pow2)
constexpr int NPIX  = NN * HW;       // 2,097,152
constexpr int NQUAD = NPIX / 4;      // 4 pixels per thread

typedef float v4f __attribute__((ext_vector_type(4)));
typedef int   v4i __attribute__((ext_vector_type(4)));

// Falsification probe for the service-rate-bound theory: max issue-side MLP.
// 4 pixels/thread -> 24 independent gather float4s in flight, dwordx4 streams,
// 9 dwordx4 planar stores. If still ~72 us, the bound is downstream (L2-miss
// service rate for random-line traffic), and we are at the roofline.
__global__ __launch_bounds__(256) void interp_quad(
    const int*   __restrict__ p2f,   // [N*H*W]
    const float* __restrict__ bary,  // [N*H*W, 3]
    const float* __restrict__ attr,  // [N*NF, 3, D] -> 6 float4 per face
    float*       __restrict__ out)   // [N, D+1, H, W]
{
    int t = blockIdx.x * blockDim.x + threadIdx.x;
    if (t >= NQUAD) return;
    int i0 = t << 2;                 // first of 4 consecutive pixels

    // --- streamed inputs, one dwordx4 each ---
    v4i ff = __builtin_nontemporal_load((const v4i*)p2f + t);
    const v4f* bp = (const v4f*)(bary + 12 * (size_t)t);   // 48 B, 16-aligned
    v4f bA = __builtin_nontemporal_load(bp + 0);
    v4f bB = __builtin_nontemporal_load(bp + 1);
    v4f bC = __builtin_nontemporal_load(bp + 2);

    // unpack [pixel][3] barycentrics from the 3 vectors
    bool vld[4] = { ff.x >= 0, ff.y >= 0, ff.z >= 0, ff.w >= 0 };
    int  f[4]   = { vld[0] ? ff.x : 0, vld[1] ? ff.y : 0,
                    vld[2] ? ff.z : 0, vld[3] ? ff.w : 0 };
    float w0[4] = { bA.x, bA.w, bB.z, bC.y };
    float w1[4] = { bA.y, bB.x, bB.w, bC.z };
    float w2[4] = { bA.z, bB.y, bC.x, bC.w };
    #pragma unroll
    for (int k = 0; k < 4; ++k)
        if (!vld[k]) { w0[k] = 0.0f; w1[k] = 0.0f; w2[k] = 0.0f; }

    // --- 24 independent 16 B gather loads ---
    v4f c[4][6];
    #pragma unroll
    for (int k = 0; k < 4; ++k) {
        const v4f* a = (const v4f*)attr + (size_t)f[k] * 6;
        #pragma unroll
        for (int j = 0; j < 6; ++j) c[k][j] = a[j];
    }

    // --- blend: lo = ch0-3, hi = ch4-7 per pixel ---
    v4f lo[4], hi[4];
    #pragma unroll
    for (int k = 0; k < 4; ++k) {
        lo[k] = w0[k] * c[k][0] + w1[k] * c[k][2] + w2[k] * c[k][4];
        hi[k] = w0[k] * c[k][1] + w1[k] * c[k][3] + w2[k] * c[k][5];
    }

    // --- planar output [N, 9, H, W]: 9 dwordx4 stores (4 adjacent pixels) ---
    int n = i0 >> 18;                // i0 / HW
    int p = i0 & (HW - 1);           // i0 % HW, multiple of 4 -> 16 B aligned
    float* ob = out + (size_t)n * (DD + 1) * HW + p;

    #pragma unroll
    for (int d = 0; d < 4; ++d) {
        v4f v = { lo[0][d], lo[1][d], lo[2][d], lo[3][d] };
        __builtin_nontemporal_store(v, (v4f*)(ob + (size_t)d * HW));
    }
    #pragma unroll
    for (int d = 0; d < 4; ++d) {
        v4f v = { hi[0][d], hi[1][d], hi[2][d], hi[3][d] };
        __builtin_nontemporal_store(v, (v4f*)(ob + (size_t)(d + 4) * HW));
    }
    v4f vis = { vld[0] ? 1.0f : 0.0f, vld[1] ? 1.0f : 0.0f,
                vld[2] ? 1.0f : 0.0f, vld[3] ? 1.0f : 0.0f };
    __builtin_nontemporal_store(vis, (v4f*)(ob + (size_t)DD * HW));
}

extern "C" void kernel_launch(void* const* d_in, const int* in_sizes, int n_in,
                              void* d_out, int out_size, void* d_ws, size_t ws_size,
                              hipStream_t stream) {
    const int*   p2f  = (const int*)d_in[0];
    const float* bary = (const float*)d_in[1];
    const float* attr = (const float*)d_in[2];
    float*       out  = (float*)d_out;

    const int block = 256;
    const int grid  = (NQUAD + block - 1) / block;   // 2048 blocks
    interp_quad<<<grid, block, 0, stream>>>(p2f, bary, attr, out);
}

// Round 6
// 182.772 us; speedup vs baseline: 1.1171x; 1.1171x over previous
//
#include <hip/hip_runtime.h>

// Problem constants (from reference): N=8, H=512, W=512, K=1, NF=100000, D=8
#define NN 8
#define HH 512
#define WW 512
#define DD 8

constexpr int HW   = HH * WW;        // 262144 (pow2)
constexpr int NPIX = NN * HW;        // 2,097,152
constexpr int PPB  = 256;            // pixels per block (= block size)
constexpr int CST  = PPB + 4;        // padded pixel-stride for chunk LDS (bank spread)

typedef float v4f __attribute__((ext_vector_type(4)));

// Best-measured structure (round 4): cooperative coalesced gather.
// Session conclusion: 4 structurally different kernels (scalar, pair-vectorized,
// this one, quad-MLP probe) all pin at 3.26-3.42 TB/s blended service rate;
// duration == bytes / 3.4 TB/s in every case. Traffic is at the compulsory
// floor (attr gather ~166 B/unique face vs 128-192 B sector floor for 96 B
// rows; streams/writes exact). Bound: L2-miss service rate (~0.9 miss/cy/XCD)
// for the random-line component — issue-side MLP/occupancy/request-count all
// proven neutral. Face-sorted and range-partitioned alternatives are
// traffic-negative (random hop on 16 B records is less dense than on 96 B
// attr rows; face-ordered output scatter touches 9 lines/pixel).
__global__ __launch_bounds__(256) void interp_coop(
    const int*   __restrict__ p2f,   // [N*H*W] packed face index, -1 = empty
    const float* __restrict__ bary,  // [N*H*W, 3]
    const float* __restrict__ attr,  // [N*NF, 3, D] -> 6 float4 per face
    float*       __restrict__ out)   // [N, D+1, H, W]
{
    __shared__ int fIdx[PPB];
    __shared__ v4f chunks[6 * CST];

    const int t = threadIdx.x;
    const int i = blockIdx.x * PPB + t;   // this thread's pixel

    // --- per-pixel stream loads ---
    int f = p2f[i];
    bool valid = f >= 0;
    fIdx[t] = valid ? f : 0;

    size_t bi = (size_t)i * 3;
    float b0 = bary[bi + 0];
    float b1 = bary[bi + 1];
    float b2 = bary[bi + 2];
    if (!valid) { b0 = 0.0f; b1 = 0.0f; b2 = 0.0f; }

    __syncthreads();

    // --- cooperative coalesced gather: consecutive lanes load consecutive
    //     16 B chunks of the SAME face -> VMEM coalescer merges to ~1.5
    //     line-requests/face ---
    const v4f* ap = (const v4f*)attr;
    #pragma unroll
    for (int j = 0; j < 6; ++j) {
        int w = j * PPB + t;
        int p = w / 6;                // pixel within block
        int c = w - p * 6;            // chunk within face
        int ff = fIdx[p];
        chunks[c * CST + p] = ap[(size_t)ff * 6 + c];
    }

    __syncthreads();

    // --- blend (phase-2 LDS reads conflict-free) ---
    v4f x0 = chunks[0 * CST + t];
    v4f x1 = chunks[1 * CST + t];
    v4f y0 = chunks[2 * CST + t];
    v4f y1 = chunks[3 * CST + t];
    v4f z0 = chunks[4 * CST + t];
    v4f z1 = chunks[5 * CST + t];

    v4f lo = b0 * x0 + b1 * y0 + b2 * z0;   // ch0-3
    v4f hi = b0 * x1 + b1 * y1 + b2 * z1;   // ch4-7

    // --- planar output [N, D+1, H, W], coalesced per plane ---
    int n = i >> 18;
    int p = i & (HW - 1);
    float* ob = out + (size_t)n * (DD + 1) * HW + p;

    __builtin_nontemporal_store(lo.x, ob + 0 * (size_t)HW);
    __builtin_nontemporal_store(lo.y, ob + 1 * (size_t)HW);
    __builtin_nontemporal_store(lo.z, ob + 2 * (size_t)HW);
    __builtin_nontemporal_store(lo.w, ob + 3 * (size_t)HW);
    __builtin_nontemporal_store(hi.x, ob + 4 * (size_t)HW);
    __builtin_nontemporal_store(hi.y, ob + 5 * (size_t)HW);
    __builtin_nontemporal_store(hi.z, ob + 6 * (size_t)HW);
    __builtin_nontemporal_store(hi.w, ob + 7 * (size_t)HW);
    __builtin_nontemporal_store(valid ? 1.0f : 0.0f, ob + 8 * (size_t)HW);
}

extern "C" void kernel_launch(void* const* d_in, const int* in_sizes, int n_in,
                              void* d_out, int out_size, void* d_ws, size_t ws_size,
                              hipStream_t stream) {
    const int*   p2f  = (const int*)d_in[0];
    const float* bary = (const float*)d_in[1];
    const float* attr = (const float*)d_in[2];
    float*       out  = (float*)d_out;

    const int grid = NPIX / PPB;      // 8192 blocks
    interp_coop<<<grid, PPB, 0, stream>>>(p2f, bary, attr, out);
}